// Round 3
// baseline (13.372 us; speedup 1.0000x reference)
//
#include <hip/hip_runtime.h>
#include <math.h>

namespace {

constexpr int B_ = 128;
constexpr int T_ = 4096;
constexpr int U_ = 128;
constexpr int F_ = 32;
constexpr int K_ = 31;
constexpr int WIN_ = 7;
constexpr int SLICES = 4;
constexpr int SLICE_W = T_ / SLICES;   // 1024 columns per slice-block
constexpr int NTHREADS = 256;

// One block per (slice, batch-row).
//  Phase A (all blocks): stream align=0 / next_state=state for the slice,
//    gated only on the state load (no prev dependency).
//  Phase B (window-intersecting blocks only): compute the 7-wide window
//    softmax and overwrite this slice's window columns. Same-block overwrite
//    is ordered by __syncthreads (compiler drains vmcnt(0) before s_barrier).
__global__ __launch_bounds__(NTHREADS) void lsa_kernel(
    const float* __restrict__ query,    // B*U
    const float* __restrict__ state,    // B*T
    const float* __restrict__ memory,   // B*T*U
    const float* __restrict__ conv_w,   // K*1*F
    const float* __restrict__ conv_b,   // F
    const float* __restrict__ loc_w,    // F*U
    const float* __restrict__ v_a,      // U
    const float* __restrict__ b_a,      // U
    const int*   __restrict__ prev,     // B
    float* __restrict__ out_align,      // B*T
    float* __restrict__ out_state,      // B*T
    float* __restrict__ out_maxattn)    // B (stored as float)
{
    const int b     = blockIdx.y;
    const int slice = blockIdx.x;
    const int tid   = threadIdx.x;
    const int base  = slice * SLICE_W;
    const size_t row = (size_t)b * T_;

    const int pm = prev[b];            // scalar load, concurrent with state load

    // ---- Phase A: stream the slice immediately (only dep: state load)
    const float4 sv = reinterpret_cast<const float4*>(state + row + base)[tid];
    reinterpret_cast<float4*>(out_align + row + base)[tid] =
        make_float4(0.f, 0.f, 0.f, 0.f);
    reinterpret_cast<float4*>(out_state + row + base)[tid] = sv;

    const int lo = max(0, pm - 4);
    const int hi = min(T_ - 1, pm + 2);
    const int w  = hi - lo + 1;        // 3..7, window always contains pm

    const bool has_window = (base <= hi) && (base + SLICE_W > lo);
    if (!has_window) return;           // block-uniform branch

    __shared__ float s_loc[WIN_][F_];  // conv features at window positions
    __shared__ float s_energy[WIN_];
    __shared__ float s_align[WIN_];
    __shared__ int   s_amax;

    const int j    = tid >> 5;         // 0..7 window slot
    const int lane = tid & 31;         // 32 lanes cover U in float4s

    // issue window memory loads early (L2/L3-hot across replays)
    float4 mv = make_float4(0.f, 0.f, 0.f, 0.f);
    if (j < w)
        mv = reinterpret_cast<const float4*>(memory + (row + lo + j) * U_)[lane];
    const float4 q4  = reinterpret_cast<const float4*>(query + (size_t)b * U_)[lane];
    const float4 va4 = reinterpret_cast<const float4*>(v_a)[lane];
    const float4 ba4 = reinterpret_cast<const float4*>(b_a)[lane];

    // ---- conv features: one thread per (window pos, filter)
    if (tid < w * F_) {
        const int cj = tid / F_;
        const int f  = tid % F_;
        const int t  = lo + cj;
        float acc = conv_b[f];
        #pragma unroll
        for (int k = 0; k < K_; ++k) {
            const int src = t + k - (K_ / 2);
            const float svv = (src >= 0 && src < T_) ? state[row + src] : 0.f;
            acc += svv * conv_w[k * F_ + f];
        }
        s_loc[cj][f] = acc;
    }
    __syncthreads();   // also drains Phase A stores (vmcnt(0) before barrier)

    // ---- energy, all 7 positions in one pass
    float e = 0.f;
    if (j < w) {
        float4 pl = make_float4(0.f, 0.f, 0.f, 0.f);
        #pragma unroll
        for (int f = 0; f < F_; ++f) {
            const float lf = s_loc[j][f];
            const float4 lw = reinterpret_cast<const float4*>(loc_w + f * U_)[lane];
            pl.x += lf * lw.x; pl.y += lf * lw.y;
            pl.z += lf * lw.z; pl.w += lf * lw.w;
        }
        e  = va4.x * tanhf(mv.x + q4.x + pl.x + ba4.x);
        e += va4.y * tanhf(mv.y + q4.y + pl.y + ba4.y);
        e += va4.z * tanhf(mv.z + q4.z + pl.z + ba4.z);
        e += va4.w * tanhf(mv.w + q4.w + pl.w + ba4.w);
    }
    #pragma unroll
    for (int off = 16; off > 0; off >>= 1)
        e += __shfl_xor(e, off);
    if (lane == 0 && j < w) s_energy[j] = e;
    __syncthreads();

    // ---- softmax over the window + first-occurrence argmax
    if (tid == 0) {
        float mx = s_energy[0];
        for (int jj = 1; jj < w; ++jj) mx = fmaxf(mx, s_energy[jj]);
        float a[WIN_];
        float sum = 0.f;
        for (int jj = 0; jj < w; ++jj) { a[jj] = expf(s_energy[jj] - mx); sum += a[jj]; }
        const float inv = 1.f / sum;
        float best = -1.f; int bj = 0;
        for (int jj = 0; jj < w; ++jj) {
            const float av = a[jj] * inv;
            s_align[jj] = av;
            if (av > best) { best = av; bj = jj; }
        }
        s_amax = lo + bj;
    }
    __syncthreads();

    // ---- Phase B fixup: overwrite this slice's window columns
    if (tid < w) {
        const int t = lo + tid;
        if (t >= base && t < base + SLICE_W) {
            const float a = s_align[tid];
            out_align[row + t] = a;
            out_state[row + t] = state[row + t] + a;
        }
    }
    if (tid == 0 && pm >= base && pm < base + SLICE_W)
        out_maxattn[b] = (float)s_amax;
}

} // namespace

extern "C" void kernel_launch(void* const* d_in, const int* in_sizes, int n_in,
                              void* d_out, int out_size, void* d_ws, size_t ws_size,
                              hipStream_t stream) {
    const float* query  = (const float*)d_in[0];
    const float* state  = (const float*)d_in[1];
    const float* memory = (const float*)d_in[2];
    const float* conv_w = (const float*)d_in[3];
    const float* conv_b = (const float*)d_in[4];
    const float* loc_w  = (const float*)d_in[5];
    const float* v_a    = (const float*)d_in[6];
    const float* b_a    = (const float*)d_in[7];
    const int*   prev   = (const int*)d_in[8];

    float* out = (float*)d_out;
    float* out_align   = out;                       // B*T
    float* out_state   = out + (size_t)B_ * T_;     // B*T
    float* out_maxattn = out + (size_t)2 * B_ * T_; // B

    dim3 grid(SLICES, B_);
    lsa_kernel<<<grid, NTHREADS, 0, stream>>>(
        query, state, memory, conv_w, conv_b, loc_w, v_a, b_a, prev,
        out_align, out_state, out_maxattn);
}